// Round 1
// baseline (829.766 us; speedup 1.0000x reference)
//
#include <hip/hip_runtime.h>

#define B_  16384
#define F_  26
#define V_  100000
#define D_  64
#define H1_ 256
#define H2_ 128

// ---------------------------------------------------------------------------
// Kernel A: embedding gather + FM second-order.
// 16 lanes per batch row, each lane owns one float4 chunk of D=64.
// fm[b][d] = 0.005 * ((sum_f raw)^2 - sum_f raw^2)   (0.1 scale folded in)
// fmsum[b] = sum_d fm[b][d]
// ---------------------------------------------------------------------------
__global__ __launch_bounds__(256) void fm_gather_kernel(
    const int* __restrict__ cat, const float* __restrict__ W2,
    float* __restrict__ fm, float* __restrict__ fmsum)
{
    int t   = blockIdx.x * 256 + threadIdx.x;
    int row = t >> 4;
    int sub = t & 15;
    const int* ci = cat + row * F_;

    float4 s = make_float4(0.f, 0.f, 0.f, 0.f);
    float4 q = make_float4(0.f, 0.f, 0.f, 0.f);
#pragma unroll
    for (int f = 0; f < F_; ++f) {
        int idx = ci[f];
        const float4* p =
            reinterpret_cast<const float4*>(W2 + ((size_t)f * V_ + (size_t)idx) * D_) + sub;
        float4 e = *p;
        s.x += e.x; s.y += e.y; s.z += e.z; s.w += e.w;
        q.x += e.x * e.x; q.y += e.y * e.y; q.z += e.z * e.z; q.w += e.w * e.w;
    }
    float4 fmv;
    fmv.x = 0.005f * (s.x * s.x - q.x);
    fmv.y = 0.005f * (s.y * s.y - q.y);
    fmv.z = 0.005f * (s.z * s.z - q.z);
    fmv.w = 0.005f * (s.w * s.w - q.w);
    reinterpret_cast<float4*>(fm)[t] = fmv;

    float r1 = (fmv.x + fmv.y) + (fmv.z + fmv.w);
#pragma unroll
    for (int o = 1; o < 16; o <<= 1) r1 += __shfl_xor(r1, o, 16);
    if (sub == 0) fmsum[row] = r1;
}

__device__ __forceinline__ float sigmoidf(float x)
{
    return 1.0f / (1.0f + __expf(-x));
}

// ---------------------------------------------------------------------------
// Kernel B: 3-layer sigmoid MLP + final sum. One block = 32 batch rows.
// GEMM1: thread = h1 column (256). Weight column in VGPRs, fm row streamed
//        via wave-uniform (scalar) loads from global.
// GEMM2: thread = (h2 column 0..127, row-half). Same pattern against the h1
//        tile written to global ws (same-block visibility via __syncthreads).
// Epilogue: h2 * W_out reduced across 128 columns through LDS.
// ---------------------------------------------------------------------------
__global__ __launch_bounds__(256) void mlp_kernel(
    const float* __restrict__ fm, const float* __restrict__ fmsum,
    const float* __restrict__ W1, const float* __restrict__ b1,
    const float* __restrict__ W2w, const float* __restrict__ b2,
    const float* __restrict__ Wout, const float* __restrict__ bout,
    const float* __restrict__ bias, float* __restrict__ h1g,
    float* __restrict__ out)
{
    const int row0 = blockIdx.x * 32;
    const int tid  = threadIdx.x;

    // ---- GEMM1: fm[32x64] @ W1[64x256] -> sigmoid -> h1 (global ws) ----
    {
        float w[D_];
#pragma unroll
        for (int d = 0; d < D_; ++d) w[d] = W1[d * H1_ + tid];
        float bc = b1[tid];
        for (int r = 0; r < 32; ++r) {
            const float* fr = fm + (size_t)(row0 + r) * D_;
            float a0 = bc, a1 = 0.f, a2 = 0.f, a3 = 0.f;
#pragma unroll
            for (int d = 0; d < D_; d += 4) {
                a0 += fr[d + 0] * w[d + 0];
                a1 += fr[d + 1] * w[d + 1];
                a2 += fr[d + 2] * w[d + 2];
                a3 += fr[d + 3] * w[d + 3];
            }
            float acc = (a0 + a1) + (a2 + a3);
            h1g[(size_t)(row0 + r) * H1_ + tid] = sigmoidf(acc);
        }
    }
    __syncthreads();

    // ---- GEMM2: h1[32x256] @ W2w[256x128] -> sigmoid -> * Wout ----
    __shared__ float red[32][128];
    {
        const int c     = tid & 127;
        const int half  = tid >> 7;
        const int rbase = row0 + half * 16;
        float bb = b2[c];
        float acc[16];
#pragma unroll
        for (int r = 0; r < 16; ++r) acc[r] = bb;

        for (int kc = 0; kc < H1_ / 8; ++kc) {
            float wv[8];
#pragma unroll
            for (int j = 0; j < 8; ++j) wv[j] = W2w[(kc * 8 + j) * H2_ + c];
#pragma unroll
            for (int r = 0; r < 16; ++r) {
                const float* hr = h1g + (size_t)(rbase + r) * H1_ + kc * 8;
#pragma unroll
                for (int j = 0; j < 8; ++j) acc[r] += hr[j] * wv[j];
            }
        }
        float wo = Wout[c];
#pragma unroll
        for (int r = 0; r < 16; ++r) {
            red[half * 16 + r][c] = sigmoidf(acc[r]) * wo;
        }
    }
    __syncthreads();

    // ---- reduce 128 columns per row + final sum ----
    {
        int rr = tid >> 3;   // 0..31
        int jj = tid & 7;    // 0..7
        float p = 0.f;
#pragma unroll
        for (int m = 0; m < 16; ++m) p += red[rr][jj * 16 + m];
        __shared__ float red2[32][8];
        red2[rr][jj] = p;
        __syncthreads();
        if (tid < 32) {
            float v = 0.f;
#pragma unroll
            for (int j = 0; j < 8; ++j) v += red2[tid][j];
            out[row0 + tid] = v + bout[0] + bias[0] + fmsum[row0 + tid];
        }
    }
}

extern "C" void kernel_launch(void* const* d_in, const int* in_sizes, int n_in,
                              void* d_out, int out_size, void* d_ws, size_t ws_size,
                              hipStream_t stream)
{
    const int*   cat  = (const int*)  d_in[0];
    const float* W2   = (const float*)d_in[1];
    const float* W1   = (const float*)d_in[2];
    const float* b1   = (const float*)d_in[3];
    const float* W2w  = (const float*)d_in[4];
    const float* b2   = (const float*)d_in[5];
    const float* Wout = (const float*)d_in[6];
    const float* bout = (const float*)d_in[7];
    const float* bias = (const float*)d_in[8];
    float* out = (float*)d_out;

    float* fm    = (float*)d_ws;                 // B*64 f32  (4 MB)
    float* fmsum = fm + (size_t)B_ * D_;         // B f32     (64 KB)
    float* h1g   = fmsum + B_;                   // B*256 f32 (16 MB)

    fm_gather_kernel<<<(B_ * 16) / 256, 256, 0, stream>>>(cat, W2, fm, fmsum);
    mlp_kernel<<<B_ / 32, 256, 0, stream>>>(fm, fmsum, W1, b1, W2w, b2,
                                            Wout, bout, bias, h1g, out);
}

// Round 2
// 791.991 us; speedup vs baseline: 1.0477x; 1.0477x over previous
//
#include <hip/hip_runtime.h>

#define B_  16384
#define F_  26
#define V_  100000
#define D_  64
#define H1_ 256
#define H2_ 128
#define RPB 32           // batch rows per block
#define FMP 68           // fm LDS row stride in floats (pad 64->68, keeps 16B align)

__device__ __forceinline__ float sigmoidf(float x)
{
    return 1.0f / (1.0f + __expf(-x));
}

// One block = 32 batch rows, 256 threads, everything fused:
//  P1 gather+FM (8 threads/row, 2x float4 per thread) -> fm in LDS
//  P2 GEMM1 fm[32x64]@W1[64x256], thread=column, fm via uniform LDS b128 broadcast
//  P3 GEMM2 h1[32x256]@W2[256x128], wave=(row-half, 64 cols), h1 via uniform LDS b128
//  P4 epilogue: 64-lane butterfly reduce over columns + fmsum + biases
__global__ __launch_bounds__(256, 2) void fused_deepfm_kernel(
    const int*   __restrict__ cat,  const float* __restrict__ W2,
    const float* __restrict__ W1,   const float* __restrict__ b1,
    const float* __restrict__ W2w,  const float* __restrict__ b2,
    const float* __restrict__ Wout, const float* __restrict__ bout,
    const float* __restrict__ bias, float* __restrict__ out)
{
    __shared__ float fm[RPB][FMP];
    __shared__ float h1s[RPB][H1_];
    __shared__ float fmsum[RPB];
    __shared__ float wpart[4][16];

    const int tid  = threadIdx.x;
    const int row0 = blockIdx.x * RPB;

    // ---------------- P1: embedding gather + FM second-order ----------------
    {
        const int r   = tid >> 3;        // 0..31 local row
        const int sub = tid & 7;         // 0..7, owns d in [sub*4,+4) and [32+sub*4,+4)
        const int* ci = cat + (size_t)(row0 + r) * F_;

        float4 s0 = {0.f,0.f,0.f,0.f}, s1 = {0.f,0.f,0.f,0.f};
        float4 q0 = {0.f,0.f,0.f,0.f}, q1 = {0.f,0.f,0.f,0.f};
#pragma unroll
        for (int f = 0; f < F_; ++f) {
            int idx = ci[f];
            const float4* base =
                reinterpret_cast<const float4*>(W2 + ((size_t)f * V_ + (size_t)idx) * D_);
            float4 a = base[sub];        // lanes sub=0..7 -> contiguous 128B
            float4 b = base[sub + 8];    // next contiguous 128B
            s0.x += a.x; s0.y += a.y; s0.z += a.z; s0.w += a.w;
            s1.x += b.x; s1.y += b.y; s1.z += b.z; s1.w += b.w;
            q0.x += a.x*a.x; q0.y += a.y*a.y; q0.z += a.z*a.z; q0.w += a.w*a.w;
            q1.x += b.x*b.x; q1.y += b.y*b.y; q1.z += b.z*b.z; q1.w += b.w*b.w;
        }
        // emb = raw*0.1 ; fm = 0.5*(s^2 - q) on scaled -> 0.005*(s_raw^2 - q_raw)
        float4 f0, f1;
        f0.x = 0.005f*(s0.x*s0.x - q0.x); f0.y = 0.005f*(s0.y*s0.y - q0.y);
        f0.z = 0.005f*(s0.z*s0.z - q0.z); f0.w = 0.005f*(s0.w*s0.w - q0.w);
        f1.x = 0.005f*(s1.x*s1.x - q1.x); f1.y = 0.005f*(s1.y*s1.y - q1.y);
        f1.z = 0.005f*(s1.z*s1.z - q1.z); f1.w = 0.005f*(s1.w*s1.w - q1.w);

        *reinterpret_cast<float4*>(&fm[r][sub * 4])      = f0;
        *reinterpret_cast<float4*>(&fm[r][32 + sub * 4]) = f1;

        float p = (f0.x + f0.y) + (f0.z + f0.w) + (f1.x + f1.y) + (f1.z + f1.w);
        p += __shfl_xor(p, 1);
        p += __shfl_xor(p, 2);
        p += __shfl_xor(p, 4);
        if (sub == 0) fmsum[r] = p;
    }
    __syncthreads();

    // ---------------- P2: GEMM1 + sigmoid -> h1s ----------------
    {
        float wc[D_];
#pragma unroll
        for (int d = 0; d < D_; ++d) wc[d] = W1[d * H1_ + tid];   // coalesced, L2
        const float bc = b1[tid];
#pragma unroll 4
        for (int r = 0; r < RPB; ++r) {
            float a0 = bc, a1 = 0.f, a2 = 0.f, a3 = 0.f;
#pragma unroll
            for (int d4 = 0; d4 < D_ / 4; ++d4) {
                float4 fv = *reinterpret_cast<const float4*>(&fm[r][d4 * 4]); // broadcast
                a0 += fv.x * wc[d4*4 + 0];
                a1 += fv.y * wc[d4*4 + 1];
                a2 += fv.z * wc[d4*4 + 2];
                a3 += fv.w * wc[d4*4 + 3];
            }
            h1s[r][tid] = sigmoidf((a0 + a1) + (a2 + a3));
        }
    }
    __syncthreads();

    // ---------------- P3: GEMM2 + sigmoid*Wout, butterfly reduce ----------------
    {
        const int wid  = tid >> 6;            // wave 0..3
        const int lane = tid & 63;
        const int half = wid >> 1;            // row half: 0 -> rows 0..15, 1 -> 16..31
        const int c    = ((wid & 1) << 6) + lane;   // h2 column 0..127
        const int rb   = half * 16;

        const float bb = b2[c];
        float acc[16];
#pragma unroll
        for (int r = 0; r < 16; ++r) acc[r] = bb;

        for (int kc = 0; kc < H1_ / 8; ++kc) {
            float wv[8];
#pragma unroll
            for (int j = 0; j < 8; ++j) wv[j] = W2w[(kc*8 + j) * H2_ + c]; // coalesced, L2
#pragma unroll
            for (int r = 0; r < 16; ++r) {
                const float4* hp = reinterpret_cast<const float4*>(&h1s[rb + r][kc * 8]);
                float4 h0 = hp[0], h4 = hp[1];  // uniform LDS b128 broadcast
                acc[r] += h0.x*wv[0] + h0.y*wv[1] + h0.z*wv[2] + h0.w*wv[3]
                        + h4.x*wv[4] + h4.y*wv[5] + h4.z*wv[6] + h4.w*wv[7];
            }
        }
        const float wo = Wout[c];
#pragma unroll
        for (int r = 0; r < 16; ++r) {
            float v = sigmoidf(acc[r]) * wo;
            v += __shfl_xor(v, 32);
            v += __shfl_xor(v, 16);
            v += __shfl_xor(v, 8);
            v += __shfl_xor(v, 4);
            v += __shfl_xor(v, 2);
            v += __shfl_xor(v, 1);
            if (lane == 0) wpart[wid][r] = v;
        }
    }
    __syncthreads();

    // ---------------- P4: final sum ----------------
    if (tid < RPB) {
        const int half = tid >> 4;
        const int r    = tid & 15;
        out[row0 + tid] = wpart[2*half][r] + wpart[2*half + 1][r]
                        + bout[0] + bias[0] + fmsum[tid];
    }
}

extern "C" void kernel_launch(void* const* d_in, const int* in_sizes, int n_in,
                              void* d_out, int out_size, void* d_ws, size_t ws_size,
                              hipStream_t stream)
{
    const int*   cat  = (const int*)  d_in[0];
    const float* W2   = (const float*)d_in[1];
    const float* W1   = (const float*)d_in[2];
    const float* b1   = (const float*)d_in[3];
    const float* W2w  = (const float*)d_in[4];
    const float* b2   = (const float*)d_in[5];
    const float* Wout = (const float*)d_in[6];
    const float* bout = (const float*)d_in[7];
    const float* bias = (const float*)d_in[8];
    float* out = (float*)d_out;

    fused_deepfm_kernel<<<B_ / RPB, 256, 0, stream>>>(
        cat, W2, W1, b1, W2w, b2, Wout, bout, bias, out);
}